// Round 9
// baseline (384.565 us; speedup 1.0000x reference)
//
#include <hip/hip_runtime.h>

// Slot Attention fwd, B=8 N=2048 D=256 S=8 H=256 ITERS=3.  All f32.
// ONE persistent kernel. Fence-free grid barriers (arrive/go atomic flags +
// s_waitcnt vmcnt(0)); cross-block activations via agent-scope atomic stores
// (write-through) / device atomicAdd, read as normal loads of per-iteration
// versioned buffers (fresh addresses -> always coherent). Weights & inputs are
// read-only -> stay hot in per-XCD L2 across all phases (no acquire fences!).
//   Pg[s] = diag(g_in[s]) * Wk[s]^T Wq[s]
//   qg[b,s] = Pg[s]*sn + qcon[s],  qc = sn.vq[s] + c0[s]
//   dots[b,s,n] = SCALE*( xn[b,n,:].qg[b,s,:] + qc )
//   updates = (Wv.(ax*g_in))/rowsum + cv
// Phases/iter: dots -> gru(upd+gh+gi+GRU) -> mlp(LN+W1+W2+res) -> q(LN+Pg).

#define BB 8
#define NT 2048
#define DD 256
#define SS 8
#define HH 256
#define GRID 256

static constexpr float F_EPS   = 1e-8f;
static constexpr float F_LNEPS = 1e-5f;
static constexpr float F_SCALE = 0.0625f;   // 256^-0.5

__device__ __forceinline__ float wredsum(float v) {
#pragma unroll
  for (int m = 32; m > 0; m >>= 1) v += __shfl_xor(v, m, 64);
  return v;
}
__device__ __forceinline__ float sigm(float x) { return 1.f / (1.f + __expf(-x)); }
__device__ __forceinline__ float tanhfast(float x) {
  float ax = fabsf(x);
  float e = __expf(2.f * ax);
  float t2 = 1.f - 2.f / (e + 1.f);
  return x < 0.f ? -t2 : t2;
}
__device__ __forceinline__ int x2i(int bb, int dd) { return bb*288 + (dd>>5)*36 + (dd&31); }

// agent-scope write-through store (reaches coherence point; no bulk flush needed)
__device__ __forceinline__ void scstore(float* p, float v) {
  __hip_atomic_store(p, v, __ATOMIC_RELAXED, __HIP_MEMORY_SCOPE_AGENT);
}

// fence-free grid barrier: per-wave vmcnt drain, then arrive/go atomic flags.
__device__ __forceinline__ void gbar(int* arrive, int* go, int ph) {
  asm volatile("s_waitcnt vmcnt(0)" ::: "memory");   // my stores reached coherence pt
  __syncthreads();
  if (blockIdx.x == 0) {
    if (threadIdx.x > 0) {
      while (__hip_atomic_load(&arrive[threadIdx.x * 32], __ATOMIC_RELAXED,
                               __HIP_MEMORY_SCOPE_AGENT) < ph)
        __builtin_amdgcn_s_sleep(1);
    }
    __syncthreads();
    if (threadIdx.x == 0)
      __hip_atomic_store(go, ph, __ATOMIC_RELAXED, __HIP_MEMORY_SCOPE_AGENT);
  } else {
    if (threadIdx.x == 0) {
      __hip_atomic_store(&arrive[blockIdx.x * 32], ph, __ATOMIC_RELAXED,
                         __HIP_MEMORY_SCOPE_AGENT);
      while (__hip_atomic_load(go, __ATOMIC_RELAXED, __HIP_MEMORY_SCOPE_AGENT) < ph)
        __builtin_amdgcn_s_sleep(2);
    }
  }
  __syncthreads();
}

struct P {
  const float *inputs,*noise,*smu,*slsig,*g_in,*b_in,*g_ns,*b_ns,*g_pf,*b_pf;
  const float *Wq,*bq,*Wk,*bk,*Wv,*bv,*Wih,*bih,*Whh,*bhh,*W1,*b1,*W2,*b2;
  float *slotsB,*qgB,*qcB,*axB,*rsB,*smB;   // versioned activation buffers
  float *ck,*cv,*vq,*qcon,*c0,*Pg;
  float *out_slots,*out_attn;
  int *arrive,*go;
};

// b-batched 32-row GEMV (round-3 proven): 256 thr; emit(o, b, v) on ALL threads.
template <typename F>
__device__ __forceinline__ void gemv32(const float* __restrict__ Wrow0,
                                       const float* __restrict__ X2,
                                       float* __restrict__ part, F emit) {
  int t = threadIdx.x;
  int ol = t >> 3, dg = t & 7;
  const float4* wr = (const float4*)(Wrow0 + (size_t)ol*256 + (size_t)dg*32);
  __syncthreads();                 // X2 staged / part free
  float acc[8] = {0.f,0.f,0.f,0.f,0.f,0.f,0.f,0.f};
#pragma unroll
  for (int j = 0; j < 8; ++j) {
    float4 w4 = wr[j];
    int xo = dg*36 + 4*j;
#pragma unroll
    for (int bbi = 0; bbi < 8; ++bbi) {
      float4 x4 = *(const float4*)&X2[bbi*288 + xo];
      acc[bbi] = fmaf(w4.x,x4.x, fmaf(w4.y,x4.y, fmaf(w4.z,x4.z, fmaf(w4.w,x4.w, acc[bbi]))));
    }
  }
#pragma unroll
  for (int bbi = 0; bbi < 8; ++bbi) part[(ol*8+bbi)*9 + dg] = acc[bbi];
  __syncthreads();
  int o = t >> 3, bbo = t & 7;
  const float* pp = &part[(o*8+bbo)*9];
  float v = ((pp[0]+pp[1])+(pp[2]+pp[3]))+((pp[4]+pp[5])+(pp[6]+pp[7]));
  emit(o, bbo, v);
}

// per-b LN stats over X2 (8x288 layout) -> lnm[8], lnr[8]
__device__ __forceinline__ void ln_stats(const float* X2, float* lnm, float* lnr) {
  int t = threadIdx.x;
  int b = t >> 5, dg = t & 31;
  float s = 0.f, q = 0.f;
#pragma unroll
  for (int seg = 0; seg < 8; ++seg) {
    float v = X2[b*288 + seg*36 + dg];
    s += v; q += v*v;
  }
#pragma unroll
  for (int m = 1; m < 32; m <<= 1) { s += __shfl_xor(s, m, 64); q += __shfl_xor(q, m, 64); }
  if (dg == 0) {
    float mu = s*(1.f/DD);
    float var = q*(1.f/DD) - mu*mu;
    lnm[b] = mu; lnr[b] = rsqrtf(var + F_LNEPS);
  }
}

// ---- P3 / q-chain: sn=LN(slots)*g_ns+b_ns; qg=Pg.sn+qcon; qc=sn.vq+c0 ----
__device__ void phase_q(const P& p, float* smem, const float* slots_v,
                        float* qg_v, float* qc_v) {
  int blk = blockIdx.x;
  if (blk >= 64) return;
  int t = threadIdx.x;
  int s = blk & 7, rc = blk >> 3;
  float* X2s = smem; float* X2n = smem + 2304; float* part = smem + 4608;
  float* lnm = smem + 6912; float* lnr = smem + 6920;
  for (int i = t; i < 2048; i += 256) {
    int b = i >> 8, d = i & 255;
    X2s[x2i(b,d)] = slots_v[(size_t)(b*8+s)*DD + d];
  }
  __syncthreads();
  ln_stats(X2s, lnm, lnr);
  __syncthreads();
  for (int i = t; i < 2048; i += 256) {
    int b = i >> 8, d = i & 255;
    X2n[x2i(b,d)] = (X2s[x2i(b,d)] - lnm[b])*lnr[b]*p.g_ns[s*DD+d] + p.b_ns[s*DD+d];
  }
  gemv32(p.Pg + ((size_t)s*DD + rc*32)*DD, X2n, part, [&](int o,int b,float v){
    scstore(&qg_v[(size_t)(b*8+s)*DD + rc*32 + o], v + p.qcon[s*DD + rc*32 + o]);
  });
  if (rc == 0) {
    int b = t >> 5, dg = t & 31;
    float sum = 0.f;
#pragma unroll
    for (int seg = 0; seg < 8; ++seg)
      sum += X2n[b*288 + seg*36 + dg] * p.vq[s*DD + seg*32 + dg];
#pragma unroll
    for (int m = 1; m < 32; m <<= 1) sum += __shfl_xor(sum, m, 64);
    if (dg == 0) scstore(&qc_v[b*8+s], sum + p.c0[s]);
  }
}

// ---- P1: upd (redundant, full) + gh/gi tiles + GRU -> smid tile ----
__device__ void phase_gru(const P& p, float* smem, const float* slots_prev,
                          const float* ax_v, const float* rs_v, float* smid_v) {
  int blk = blockIdx.x;
  if (blk >= 64) return;
  int t = threadIdx.x;
  int s = blk & 7, jc = blk >> 3, jb = jc*32;
  float* X2s = smem; float* X2u = smem + 2304; float* X2p2 = smem + 4608;
  float* part = smem + 6912; float* redr = smem + 9216;
  if (t < 8) redr[t] = rs_v[t*8+s];
  for (int i = t; i < 2048; i += 256) {
    int b = i >> 8, d = i & 255;
    X2s[x2i(b,d)] = slots_prev[(size_t)(b*8+s)*DD + d];
  }
  __syncthreads();
  for (int i = t; i < 2048; i += 256) {
    int b = i >> 8, d = i & 255;
    X2u[x2i(b,d)] = ax_v[(size_t)(b*8+s)*DD + d] / redr[b] * p.g_in[s*DD+d];
  }
  float ghr=0.f, ghz=0.f, ghn=0.f, gir=0.f, giz=0.f, gin2=0.f;
  gemv32(p.Whh + ((size_t)s*768 + jb)*DD,     X2s, part, [&](int o,int b,float v){(void)b; ghr = v + p.bhh[s*768 + jb + o];});
  gemv32(p.Whh + ((size_t)s*768 + 256+jb)*DD, X2s, part, [&](int o,int b,float v){(void)b; ghz = v + p.bhh[s*768 + 256 + jb + o];});
  gemv32(p.Whh + ((size_t)s*768 + 512+jb)*DD, X2s, part, [&](int o,int b,float v){(void)b; ghn = v + p.bhh[s*768 + 512 + jb + o];});
  for (int tl = 0; tl < 8; ++tl)
    gemv32(p.Wv + ((size_t)s*DD + tl*32)*DD, X2u, part, [&](int o,int b,float v){
      X2p2[x2i(b, tl*32+o)] = v + p.cv[s*DD + tl*32 + o];
    });
  gemv32(p.Wih + ((size_t)s*768 + jb)*DD,     X2p2, part, [&](int o,int b,float v){(void)b; gir = v + p.bih[s*768 + jb + o];});
  gemv32(p.Wih + ((size_t)s*768 + 256+jb)*DD, X2p2, part, [&](int o,int b,float v){(void)b; giz = v + p.bih[s*768 + 256 + jb + o];});
  gemv32(p.Wih + ((size_t)s*768 + 512+jb)*DD, X2p2, part, [&](int o,int b,float v){(void)b; gin2 = v + p.bih[s*768 + 512 + jb + o];});
  int o = t >> 3, b = t & 7, d = jb + o;
  float hprev = X2s[x2i(b,d)];
  float r = sigm(gir + ghr);
  float z = sigm(giz + ghz);
  float nn2 = tanhfast(gin2 + r*ghn);
  scstore(&smid_v[(size_t)(b*8+s)*DD + d], (1.f - z)*nn2 + z*hprev);
}

// ---- P2: pre=LN(smid)*g_pf+b_pf; h1 full (redundant); W2 tile + residual ----
__device__ void phase_mlp(const P& p, float* smem, const float* smid_v,
                          float* slots_v, float* out_slots, int last) {
  int blk = blockIdx.x;
  if (blk >= 64) return;
  int t = threadIdx.x;
  int s = blk & 7, rc = blk >> 3;
  float* X2m = smem; float* X2p = smem + 2304; float* X2h = smem + 4608;
  float* part = smem + 6912; float* lnm = smem + 9216; float* lnr = smem + 9224;
  for (int i = t; i < 2048; i += 256) {
    int b = i >> 8, d = i & 255;
    X2m[x2i(b,d)] = smid_v[(size_t)(b*8+s)*DD + d];
  }
  __syncthreads();
  ln_stats(X2m, lnm, lnr);
  __syncthreads();
  for (int i = t; i < 2048; i += 256) {
    int b = i >> 8, d = i & 255;
    X2p[x2i(b,d)] = (X2m[x2i(b,d)] - lnm[b])*lnr[b]*p.g_pf[s*DD+d] + p.b_pf[s*DD+d];
  }
  for (int tl = 0; tl < 8; ++tl)
    gemv32(p.W1 + ((size_t)s*HH + tl*32)*DD, X2p, part, [&](int o,int b,float v){
      X2h[x2i(b, tl*32+o)] = fmaxf(v + p.b1[s*HH + tl*32 + o], 0.f);
    });
  gemv32(p.W2 + ((size_t)s*DD + rc*32)*HH, X2h, part, [&](int o,int b,float v){
    int d = rc*32 + o;
    size_t gi2 = (size_t)(b*8+s)*DD + d;
    float out = v + p.b2[s*DD + d] + X2m[x2i(b,d)];
    scstore(&slots_v[gi2], out);
    if (last) out_slots[gi2] = out;
  });
}

// ---- dots: LN(inputs) + dots + softmax(slots) + atomic ax/rsum ----
__device__ void phase_dots(const P& p, float* smem, const float* qg_v,
                           const float* qc_v, float* ax_v, float* rs_v,
                           int write_attn) {
  float* qgl = smem;            // 2048
  float* xt  = smem + 2048;     // 32*260
  float* dl  = smem + 10368;    // 8*33
  float* qcl = smem + 10632;    // 8
  float* rsl = smem + 10640;    // 8
  int t = threadIdx.x;
  int b = blockIdx.x >> 5;
  int chunk = blockIdx.x & 31;
  int wid = t >> 6, lane = t & 63;
  for (int i = t; i < SS*DD; i += 256) qgl[i] = qg_v[(size_t)b*SS*DD + i];
  if (t < 8) { qcl[t] = qc_v[b*8+t]; rsl[t] = 0.f; }
  int si = t >> 5, ni = t & 31;
  float axa[8] = {0.f,0.f,0.f,0.f,0.f,0.f,0.f,0.f};
  for (int tile = 0; tile < 2; ++tile) {
    int n0 = (chunk*2 + tile) * 32;
    __syncthreads();
#pragma unroll
    for (int rr = 0; rr < 8; ++rr) {
      int r = wid*8 + rr;
      const float4* src = (const float4*)(p.inputs + ((size_t)b*NT + n0 + r)*DD);
      float4 x = src[lane];
      float sv = wredsum(x.x + x.y + x.z + x.w);
      float sq = wredsum(x.x*x.x + x.y*x.y + x.z*x.z + x.w*x.w);
      float mu = sv*(1.f/DD), var = sq*(1.f/DD)-mu*mu, rs = rsqrtf(var+F_LNEPS);
      float4 o;
      o.x=(x.x-mu)*rs; o.y=(x.y-mu)*rs; o.z=(x.z-mu)*rs; o.w=(x.w-mu)*rs;
      *(float4*)&xt[r*260 + lane*4] = o;
    }
    __syncthreads();
    float acc = 0.f;
    {
      const float4* xr = (const float4*)&xt[ni*260];
      const float4* qr = (const float4*)&qgl[si*DD];
#pragma unroll 8
      for (int j = 0; j < 64; ++j) {
        float4 a4 = xr[j]; float4 b4 = qr[j];
        acc += a4.x*b4.x + a4.y*b4.y + a4.z*b4.z + a4.w*b4.w;
      }
    }
    float dot = (acc + qcl[si]) * F_SCALE;
    dl[si*33+ni] = dot;
    __syncthreads();
    float m = dl[ni];
#pragma unroll
    for (int ss2 = 1; ss2 < 8; ++ss2) m = fmaxf(m, dl[ss2*33+ni]);
    float den = 0.f;
#pragma unroll
    for (int ss2 = 0; ss2 < 8; ++ss2) den += __expf(dl[ss2*33+ni] - m);
    float a = __expf(dot - m) / den + F_EPS;
    __syncthreads();
    dl[si*33+ni] = a;
    float rv = a;
#pragma unroll
    for (int mm = 16; mm > 0; mm >>= 1) rv += __shfl_xor(rv, mm, 64);
    if (ni == 0) rsl[si] += rv;
    if (write_attn) p.out_attn[(size_t)(b*8+si)*NT + n0 + ni] = a;
    __syncthreads();
#pragma unroll
    for (int n = 0; n < 32; ++n) {
      float x = xt[n*260 + t];
#pragma unroll
      for (int ss2 = 0; ss2 < 8; ++ss2) axa[ss2] += dl[ss2*33+n] * x;
    }
  }
#pragma unroll
  for (int ss2 = 0; ss2 < 8; ++ss2)
    atomicAdd(&ax_v[(size_t)(b*8+ss2)*DD + t], axa[ss2]);
  __syncthreads();
  if (t < 8) atomicAdd(&rs_v[b*8+t], rsl[t]);
}

__global__ __launch_bounds__(256, 1) void mega(P p) {
  __shared__ __align__(16) float smem[10648];   // 42.6 KB union
  const int blk = blockIdx.x;
  const int t = threadIdx.x;
  const int wid = t >> 6, lane = t & 63;
  int ph = 0;

  // ===== A1: ck/cv, slots[0], zero ax/rs, Pg GEMM (all via scstore) =====
  if (blk < 32) {
    int s = blk >> 2, oq = blk & 3;
    float4 bi = ((const float4*)(p.b_in + s*DD))[lane];
    for (int r = 0; r < 16; ++r) {
      int o = oq*64 + wid*16 + r;
      float4 wk4 = ((const float4*)(p.Wk + ((size_t)s*DD + o)*DD))[lane];
      float4 wv4 = ((const float4*)(p.Wv + ((size_t)s*DD + o)*DD))[lane];
      float pk = wredsum(bi.x*wk4.x + bi.y*wk4.y + bi.z*wk4.z + bi.w*wk4.w);
      float pv = wredsum(bi.x*wv4.x + bi.y*wv4.y + bi.z*wv4.z + bi.w*wv4.w);
      if (lane == 0) {
        scstore(&p.ck[s*DD+o], pk + p.bk[s*DD+o]);
        scstore(&p.cv[s*DD+o], pv + p.bv[s*DD+o]);
      }
    }
  } else if (blk < 96) {
    int idx = (blk-32)*256 + t;
    int sd = idx & 2047;
    scstore(&p.slotsB[idx], p.smu[sd] + __expf(p.slsig[sd]) * p.noise[idx]);
  } else {
    for (int idx = (blk-96)*256 + t; idx < 3*16384 + 192; idx += 160*256)
      scstore(&p.axB[idx], 0.f);     // axB then rsB contiguous
  }
  {
    float* Ak = smem;
    float* Aq = smem + 1056;
    for (int tile2 = blk; tile2 < 512; tile2 += 256) {
      int s = tile2 >> 6, tile = tile2 & 63;
      int td = tile >> 3, te = tile & 7;
      int dli = t >> 5, el = t & 31;
      float acc[4] = {0.f,0.f,0.f,0.f};
      for (int o0 = 0; o0 < DD; o0 += 32) {
        __syncthreads();
        for (int i = t; i < 1024; i += 256) {
          int o = i >> 5, c = i & 31;
          Ak[o*33+c] = p.Wk[((size_t)s*DD + o0+o)*DD + td*32 + c];
          Aq[o*33+c] = p.Wq[((size_t)s*DD + o0+o)*DD + te*32 + c];
        }
        __syncthreads();
#pragma unroll 8
        for (int o = 0; o < 32; ++o) {
          float aq = Aq[o*33+el];
#pragma unroll
          for (int j = 0; j < 4; ++j)
            acc[j] += Ak[o*33 + dli*4 + j] * aq;
        }
      }
#pragma unroll
      for (int j = 0; j < 4; ++j) {
        int d = td*32 + dli*4 + j;
        scstore(&p.Pg[((size_t)s*DD + d)*DD + te*32 + el], p.g_in[s*DD + d] * acc[j]);
      }
    }
  }
  gbar(p.arrive, p.go, ++ph);

  // ===== A2: vq, qcon, c0 =====
  if (blk < 16) {
    float* cvec  = smem;
    float* part2 = smem + 256;
    int s = blk >> 1, which = blk & 1;
    const float* W = which ? p.Wk : p.Wq;
    const float* vec = which ? p.bq : p.ck;
    cvec[t] = vec[s*DD + t];
    __syncthreads();
    int og = t >> 5, eg = t & 31;
    float acc[8] = {0.f,0.f,0.f,0.f,0.f,0.f,0.f,0.f};
    for (int oi = 0; oi < 32; ++oi) {
      int o = og*32 + oi;
      float cv2 = cvec[o];
      const float4* wrow = (const float4*)(W + ((size_t)s*DD + o)*DD + eg*8);
      float4 w0 = wrow[0], w1 = wrow[1];
      acc[0] += w0.x*cv2; acc[1] += w0.y*cv2; acc[2] += w0.z*cv2; acc[3] += w0.w*cv2;
      acc[4] += w1.x*cv2; acc[5] += w1.y*cv2; acc[6] += w1.z*cv2; acc[7] += w1.w*cv2;
    }
#pragma unroll
    for (int j = 0; j < 8; ++j) part2[og*264 + eg*8 + j] = acc[j];
    __syncthreads();
    float v = 0.f;
#pragma unroll
    for (int og2 = 0; og2 < 8; ++og2) v += part2[og2*264 + t];
    if (which) scstore(&p.qcon[s*DD + t], v * p.g_in[s*DD + t]);
    else       scstore(&p.vq[s*DD + t],   v);
    if (which == 0 && t < 64) {
      float4 b4 = ((const float4*)(p.bq + s*DD))[t];
      float4 c4 = ((const float4*)(p.ck + s*DD))[t];
      float vv = wredsum(b4.x*c4.x + b4.y*c4.y + b4.z*c4.z + b4.w*c4.w);
      if (t == 0) scstore(&p.c0[s], vv);
    }
  }
  gbar(p.arrive, p.go, ++ph);

  // ===== P3_0: initial q-chain =====
  phase_q(p, smem, p.slotsB, p.qgB, p.qcB);
  gbar(p.arrive, p.go, ++ph);

  // ===== iterations =====
  for (int it = 1; it <= 3; ++it) {
    int last = (it == 3);
    phase_dots(p, smem, p.qgB + (size_t)(it-1)*16384, p.qcB + (it-1)*64,
               p.axB + (size_t)(it-1)*16384, p.rsB + (it-1)*64, last);
    gbar(p.arrive, p.go, ++ph);
    phase_gru(p, smem, p.slotsB + (size_t)(it-1)*16384,
              p.axB + (size_t)(it-1)*16384, p.rsB + (it-1)*64,
              p.smB + (size_t)(it-1)*16384);
    gbar(p.arrive, p.go, ++ph);
    phase_mlp(p, smem, p.smB + (size_t)(it-1)*16384,
              p.slotsB + (size_t)it*16384, p.out_slots, last);
    if (!last) {
      gbar(p.arrive, p.go, ++ph);
      phase_q(p, smem, p.slotsB + (size_t)it*16384,
              p.qgB + (size_t)it*16384, p.qcB + it*64);
      gbar(p.arrive, p.go, ++ph);
    }
  }
}

extern "C" void kernel_launch(void* const* d_in, const int* in_sizes, int n_in,
                              void* d_out, int out_size, void* d_ws, size_t ws_size,
                              hipStream_t stream) {
  (void)in_sizes; (void)n_in; (void)out_size; (void)ws_size;
  float* ws = (float*)d_ws;
  P p;
  p.inputs = (const float*)d_in[0];
  p.noise  = (const float*)d_in[1];
  p.smu    = (const float*)d_in[2];
  p.slsig  = (const float*)d_in[3];
  p.g_in   = (const float*)d_in[4];
  p.b_in   = (const float*)d_in[5];
  p.g_ns   = (const float*)d_in[6];
  p.b_ns   = (const float*)d_in[7];
  p.g_pf   = (const float*)d_in[8];
  p.b_pf   = (const float*)d_in[9];
  p.Wq  = (const float*)d_in[10];
  p.bq  = (const float*)d_in[11];
  p.Wk  = (const float*)d_in[12];
  p.bk  = (const float*)d_in[13];
  p.Wv  = (const float*)d_in[14];
  p.bv  = (const float*)d_in[15];
  p.Wih = (const float*)d_in[16];
  p.bih = (const float*)d_in[17];
  p.Whh = (const float*)d_in[18];
  p.bhh = (const float*)d_in[19];
  p.W1  = (const float*)d_in[20];
  p.b1  = (const float*)d_in[21];
  p.W2  = (const float*)d_in[22];
  p.b2  = (const float*)d_in[23];

  p.slotsB = ws;                      ws += 4*16384;   // slots v0..v3
  p.qgB    = ws;                      ws += 3*16384;   // qg v0..v2
  p.qcB    = ws;                      ws += 3*64;
  p.axB    = ws;                      ws += 3*16384;   // axun v1..v3
  p.rsB    = ws;                      ws += 3*64;      // contiguous after axB
  p.smB    = ws;                      ws += 3*16384;   // smid v1..v3
  p.ck     = ws;                      ws += SS*DD;
  p.cv     = ws;                      ws += SS*DD;
  p.vq     = ws;                      ws += SS*DD;
  p.qcon   = ws;                      ws += SS*DD;
  p.c0     = ws;                      ws += 64;
  p.Pg     = ws;                      ws += (size_t)SS*DD*DD;  // 2 MB
  p.arrive = (int*)ws;                ws += GRID*32;
  p.go     = (int*)ws;                ws += 32;

  p.out_slots = (float*)d_out;
  p.out_attn  = p.out_slots + BB*SS*DD;

  hipMemsetAsync((void*)p.arrive, 0, (GRID*32 + 32) * sizeof(int), stream);
  mega<<<dim3(GRID), dim3(256), 0, stream>>>(p);
}

// Round 10
// 215.675 us; speedup vs baseline: 1.7831x; 1.7831x over previous
//
#include <hip/hip_runtime.h>

// Slot Attention fwd, B=8 N=2048 D=256 S=8 H=256 ITERS=3.  All f32.
// Multi-kernel (18 launches), round-3 structure + GRU-chain collapse:
//   Pg[s]  = diag(g_in[s]) * Wk[s]^T Wq[s]        (one-time)
//   Wiv[s] = Wih[s] @ Wv[s],  ci[s] = Wih.cv + bih (one-time; upd never exists)
//   qg[b,s] = Pg[s]*sn + qcon[s],  qc = sn.vq[s] + c0[s]
//   dots[b,s,n] = SCALE*( xn[b,n,:].qg[b,s,:] + qc )
//   gi = Wiv.xv + ci,  gh = Whh.slots + bhh,  xv = ax*g_in/rsum
// xn = LN(inputs) recomputed on the fly in k_dots (never stored).

#define BB 8
#define NT 2048
#define DD 256
#define SS 8
#define HH 256

static constexpr float F_EPS   = 1e-8f;
static constexpr float F_LNEPS = 1e-5f;
static constexpr float F_SCALE = 0.0625f;   // 256^-0.5

__device__ __forceinline__ float wredsum(float v) {
#pragma unroll
  for (int m = 32; m > 0; m >>= 1) v += __shfl_xor(v, m, 64);
  return v;
}
__device__ __forceinline__ float sigm(float x) { return 1.f / (1.f + __expf(-x)); }
__device__ __forceinline__ float tanhfast(float x) {
  float ax = fabsf(x);
  float e = __expf(2.f * ax);
  float t2 = 1.f - 2.f / (e + 1.f);
  return x < 0.f ? -t2 : t2;
}
// X2 LDS layout: (b,d) -> b*288 + (d>>5)*36 + (d&31)   (bank-conflict-free)
__device__ __forceinline__ int x2i(int bb, int dd) { return bb*288 + (dd>>5)*36 + (dd&31); }
__device__ __forceinline__ int xpi(int d) { return (d>>5)*36 + (d&31); }

// ---- b-batched 32-row GEMV (round-3 proven): 256 thr; emit(o,b,v) on all threads ----
template <typename F>
__device__ __forceinline__ void gemv32(const float* __restrict__ Wrow0,
                                       const float* __restrict__ X2,
                                       float* __restrict__ part, F emit) {
  int t = threadIdx.x;
  int ol = t >> 3, dg = t & 7;
  const float4* wr = (const float4*)(Wrow0 + (size_t)ol*256 + (size_t)dg*32);
  __syncthreads();                 // X2 staged / part free
  float acc[8] = {0.f,0.f,0.f,0.f,0.f,0.f,0.f,0.f};
#pragma unroll
  for (int j = 0; j < 8; ++j) {
    float4 w4 = wr[j];
    int xo = dg*36 + 4*j;
#pragma unroll
    for (int bbi = 0; bbi < 8; ++bbi) {
      float4 x4 = *(const float4*)&X2[bbi*288 + xo];
      acc[bbi] = fmaf(w4.x,x4.x, fmaf(w4.y,x4.y, fmaf(w4.z,x4.z, fmaf(w4.w,x4.w, acc[bbi]))));
    }
  }
#pragma unroll
  for (int bbi = 0; bbi < 8; ++bbi) part[(ol*8+bbi)*9 + dg] = acc[bbi];
  __syncthreads();
  int o = t >> 3, bbo = t & 7;
  const float* pp = &part[(o*8+bbo)*9];
  float v = ((pp[0]+pp[1])+(pp[2]+pp[3]))+((pp[4]+pp[5])+(pp[6]+pp[7]));
  emit(o, bbo, v);
}

// same core but tid/part parametrized (512-thread kernels run two halves in lockstep)
template <typename F>
__device__ __forceinline__ void gemv32h(const float* __restrict__ Wrow0,
                                        const float* __restrict__ X2,
                                        float* __restrict__ part, int tid, F emit) {
  int ol = tid >> 3, dg = tid & 7;
  const float4* wr = (const float4*)(Wrow0 + (size_t)ol*256 + (size_t)dg*32);
  __syncthreads();
  float acc[8] = {0.f,0.f,0.f,0.f,0.f,0.f,0.f,0.f};
#pragma unroll
  for (int j = 0; j < 8; ++j) {
    float4 w4 = wr[j];
    int xo = dg*36 + 4*j;
#pragma unroll
    for (int bbi = 0; bbi < 8; ++bbi) {
      float4 x4 = *(const float4*)&X2[bbi*288 + xo];
      acc[bbi] = fmaf(w4.x,x4.x, fmaf(w4.y,x4.y, fmaf(w4.z,x4.z, fmaf(w4.w,x4.w, acc[bbi]))));
    }
  }
#pragma unroll
  for (int bbi = 0; bbi < 8; ++bbi) part[(ol*8+bbi)*9 + dg] = acc[bbi];
  __syncthreads();
  int o = tid >> 3, bbo = tid & 7;
  const float* pp = &part[(o*8+bbo)*9];
  float v = ((pp[0]+pp[1])+(pp[2]+pp[3]))+((pp[4]+pp[5])+(pp[6]+pp[7]));
  emit(o, bbo, v);
}

// ---- sync-free single-vector GEMV tile (32 rows x 8 dg) ----
template <typename F>
__device__ __forceinline__ void gemv_tile(const float* __restrict__ Wrow0,
                                          const float* __restrict__ xp, F emit) {
  int t = threadIdx.x;
  int ol = t >> 3, dg = t & 7;
  const float4* wr = (const float4*)(Wrow0 + (size_t)ol*256 + dg*32);
  float acc = 0.f;
#pragma unroll
  for (int j = 0; j < 8; ++j) {
    float4 w4 = wr[j];
    float4 x4 = *(const float4*)&xp[dg*36 + 4*j];
    acc = fmaf(w4.x,x4.x, fmaf(w4.y,x4.y, fmaf(w4.z,x4.z, fmaf(w4.w,x4.w, acc))));
  }
  acc += __shfl_xor(acc, 1, 64);
  acc += __shfl_xor(acc, 2, 64);
  acc += __shfl_xor(acc, 4, 64);
  if ((t & 7) == 0) emit(ol, acc);
}

// ---------------- init1: ck/cv and slots ----------------
__global__ __launch_bounds__(256) void k_init(
    const float* __restrict__ Wk, const float* __restrict__ bk,
    const float* __restrict__ Wv, const float* __restrict__ bv,
    const float* __restrict__ b_in, const float* __restrict__ smu,
    const float* __restrict__ slsig, const float* __restrict__ noise,
    float* __restrict__ ck, float* __restrict__ cv, float* __restrict__ slots) {
  int blk = blockIdx.x;
  int t = threadIdx.x;
  if (blk < 32) {
    int s = blk >> 2, oq = blk & 3;
    int wid = t >> 6, lane = t & 63;
    float4 bi = ((const float4*)(b_in + s*DD))[lane];
    for (int r = 0; r < 16; ++r) {
      int o = oq*64 + wid*16 + r;
      float4 wk4 = ((const float4*)(Wk + ((size_t)s*DD + o)*DD))[lane];
      float4 wv4 = ((const float4*)(Wv + ((size_t)s*DD + o)*DD))[lane];
      float pk = wredsum(bi.x*wk4.x + bi.y*wk4.y + bi.z*wk4.z + bi.w*wk4.w);
      float pv = wredsum(bi.x*wv4.x + bi.y*wv4.y + bi.z*wv4.z + bi.w*wv4.w);
      if (lane == 0) {
        ck[s*DD+o] = pk + bk[s*DD+o];
        cv[s*DD+o] = pv + bv[s*DD+o];
      }
    }
  } else {
    int idx = (blk-32)*256 + t;       // < B*S*D
    int sd = idx & 2047;
    slots[idx] = smu[sd] + __expf(slsig[sd]) * noise[idx];
  }
}

// ---------------- init2: Pg = diag(g_in) Wk^T Wq ; vq, qcon, c0 ----------------
__global__ __launch_bounds__(256) void k_init2(
    const float* __restrict__ Wq, const float* __restrict__ Wk,
    const float* __restrict__ bq, const float* __restrict__ ck,
    const float* __restrict__ g_in,
    float* __restrict__ Pg, float* __restrict__ vq,
    float* __restrict__ qcon, float* __restrict__ c0) {
  int blk = blockIdx.x;
  int t = threadIdx.x;
  if (blk < 512) {
    __shared__ float Ak[32*33], Aq[32*33];
    int s = blk >> 6, tile = blk & 63;
    int td = tile >> 3, te = tile & 7;
    int dl = t >> 5, el = t & 31;
    float acc[4] = {0.f,0.f,0.f,0.f};
    for (int o0 = 0; o0 < DD; o0 += 32) {
      __syncthreads();
      for (int i = t; i < 1024; i += 256) {
        int o = i >> 5, c = i & 31;
        Ak[o*33+c] = Wk[((size_t)s*DD + o0+o)*DD + td*32 + c];
        Aq[o*33+c] = Wq[((size_t)s*DD + o0+o)*DD + te*32 + c];
      }
      __syncthreads();
#pragma unroll 8
      for (int o = 0; o < 32; ++o) {
        float aq = Aq[o*33+el];
#pragma unroll
        for (int j = 0; j < 4; ++j)
          acc[j] += Ak[o*33 + dl*4 + j] * aq;
      }
    }
#pragma unroll
    for (int j = 0; j < 4; ++j) {
      int d = td*32 + dl*4 + j;
      Pg[((size_t)s*DD + d)*DD + te*32 + el] = g_in[s*DD + d] * acc[j];
    }
  } else {
    __shared__ float cvec[DD];
    __shared__ float part2[8*264];
    int idx = blk - 512;
    int s = idx >> 1, which = idx & 1;
    const float* W = which ? Wk : Wq;
    const float* vec = which ? bq : ck;
    cvec[t] = vec[s*DD + t];
    __syncthreads();
    int og = t >> 5, eg = t & 31;
    float acc[8] = {0.f,0.f,0.f,0.f,0.f,0.f,0.f,0.f};
    for (int oi = 0; oi < 32; ++oi) {
      int o = og*32 + oi;
      float cv2 = cvec[o];
      const float4* wrow = (const float4*)(W + ((size_t)s*DD + o)*DD + eg*8);
      float4 w0 = wrow[0], w1 = wrow[1];
      acc[0] += w0.x*cv2; acc[1] += w0.y*cv2; acc[2] += w0.z*cv2; acc[3] += w0.w*cv2;
      acc[4] += w1.x*cv2; acc[5] += w1.y*cv2; acc[6] += w1.z*cv2; acc[7] += w1.w*cv2;
    }
#pragma unroll
    for (int j = 0; j < 8; ++j) part2[og*264 + eg*8 + j] = acc[j];
    __syncthreads();
    float v = 0.f;
#pragma unroll
    for (int og2 = 0; og2 < 8; ++og2) v += part2[og2*264 + t];
    if (which) qcon[s*DD + t] = v * g_in[s*DD + t];
    else       vq[s*DD + t]   = v;
    if (which == 0 && t < 64) {
      float4 b4 = ((const float4*)(bq + s*DD))[t];
      float4 c4 = ((const float4*)(ck + s*DD))[t];
      float vv = wredsum(b4.x*c4.x + b4.y*c4.y + b4.z*c4.z + b4.w*c4.w);
      if (t == 0) c0[s] = vv;
    }
  }
}

// ---------------- init2b: Wiv = Wih @ Wv (tile GEMM) ; ci = Wih.cv + bih ----------------
__global__ __launch_bounds__(256) void k_init2b(
    const float* __restrict__ Wih, const float* __restrict__ Wv,
    const float* __restrict__ cv, const float* __restrict__ bih,
    float* __restrict__ Wiv, float* __restrict__ ci) {
  __shared__ float sm[2112];
  int blk = blockIdx.x;
  int t = threadIdx.x;
  if (blk < 1536) {                        // Wiv tiles: 8 slots x 24 tj x 8 td
    float* Aih = sm;          // 32*33
    float* Bv  = sm + 1056;   // 32*33
    int s = blk / 192, rem = blk % 192;
    int tj = rem >> 3, td = rem & 7;
    int dl = t >> 5, el = t & 31;
    float acc[4] = {0.f,0.f,0.f,0.f};
    for (int o0 = 0; o0 < DD; o0 += 32) {
      __syncthreads();
      for (int i = t; i < 1024; i += 256) {
        int r = i >> 5, c = i & 31;
        Aih[r*33+c] = Wih[((size_t)s*768 + tj*32 + r)*DD + o0 + c];
        Bv[r*33+c]  = Wv[((size_t)s*DD + o0 + r)*DD + td*32 + c];
      }
      __syncthreads();
#pragma unroll 8
      for (int o = 0; o < 32; ++o) {
        float bv2 = Bv[o*33+el];
#pragma unroll
        for (int j = 0; j < 4; ++j)
          acc[j] += Aih[(dl*4+j)*33 + o] * bv2;
      }
    }
#pragma unroll
    for (int j = 0; j < 4; ++j) {
      int r = tj*32 + dl*4 + j;
      Wiv[((size_t)s*768 + r)*DD + td*32 + el] = acc[j];
    }
  } else {                                 // ci: 8 slots x 24 row-tiles
    float* xp = sm;           // 288
    int idx = blk - 1536;
    int s = idx / 24, jt = idx % 24;
    xp[xpi(t)] = cv[s*DD + t];
    __syncthreads();
    gemv_tile(Wih + ((size_t)s*768 + jt*32)*DD, xp, [&](int o, float v){
      ci[s*768 + jt*32 + o] = v + bih[s*768 + jt*32 + o];
    });
  }
}

// ---------------- per-iter q-chain (round-3 verbatim): sn, qg, qc; zero ax/rs ----------------
__global__ __launch_bounds__(256) void k_q2(
    const float* __restrict__ slots, const float* __restrict__ g_ns,
    const float* __restrict__ b_ns, const float* __restrict__ Pg,
    const float* __restrict__ qcon, const float* __restrict__ vq,
    const float* __restrict__ c0,
    float* __restrict__ qg, float* __restrict__ qc,
    float* __restrict__ axun, float* __restrict__ rsum) {
  __shared__ __align__(16) float X2[8*288];
  __shared__ float part[32*8*9];
  int blk = blockIdx.x;
  int s = blk >> 3, rc = blk & 7;
  int t = threadIdx.x;
  int wid = t >> 6, lane = t & 63;
  float4 g4 = ((const float4*)(g_ns + s*DD))[lane];
  float4 p4 = ((const float4*)(b_ns + s*DD))[lane];
#pragma unroll
  for (int half = 0; half < 2; ++half) {
    int bb2 = wid + half*4;
    const float4* src = (const float4*)(slots + (size_t)(bb2*8+s)*DD);
    float4 x = src[lane];
    float sv = wredsum(x.x+x.y+x.z+x.w);
    float sq = wredsum(x.x*x.x + x.y*x.y + x.z*x.z + x.w*x.w);
    float mu = sv*(1.f/DD), var = sq*(1.f/DD)-mu*mu, rs = rsqrtf(var+F_LNEPS);
    int base = bb2*288 + (lane>>3)*36 + (lane&7)*4;
    X2[base]   = (x.x-mu)*rs*g4.x + p4.x;
    X2[base+1] = (x.y-mu)*rs*g4.y + p4.y;
    X2[base+2] = (x.z-mu)*rs*g4.z + p4.z;
    X2[base+3] = (x.w-mu)*rs*g4.w + p4.w;
  }
  if (rc == 0) {
    for (int i = t; i < 2048; i += 256) {
      int bb2 = i >> 8, dd = i & 255;
      axun[(size_t)(bb2*8+s)*DD + dd] = 0.f;     // zero accumulators for k_dots
    }
    if (t < 8) rsum[t*8+s] = 0.f;
  }
  __syncthreads();
  if (rc == 0) {           // qc for all 8 b's of this slot
    int b = t >> 5, l32 = t & 31;
    float v = 0.f;
#pragma unroll
    for (int j = 0; j < 8; ++j)
      v += X2[b*288 + j*36 + l32] * vq[s*DD + j*32 + l32];
#pragma unroll
    for (int m = 16; m > 0; m >>= 1) v += __shfl_xor(v, m, 64);
    if (l32 == 0) qc[b*8+s] = v + c0[s];
  }
  gemv32(Pg + ((size_t)s*DD + rc*32)*DD, X2, part, [&](int o,int bb2,float v){
    qg[(size_t)(bb2*8+s)*DD + rc*32 + o] = v + qcon[s*DD + rc*32 + o];
  });
}

// ---------------- heavy (round-3 verbatim): LN(inputs)+dots+softmax+ax atomics ----------------
__global__ __launch_bounds__(256) void k_dots(
    const float* __restrict__ inputs, const float* __restrict__ qg,
    const float* __restrict__ qc, float* __restrict__ axun,
    float* __restrict__ rsum, float* __restrict__ attn_out, int write_attn) {
  __shared__ __align__(16) float qgl[SS*DD];   // 8 KB
  __shared__ __align__(16) float xt[32*260];   // 33.3 KB
  __shared__ float dl[8*33];
  __shared__ float qcl[8];
  __shared__ float rsl[8];
  int t = threadIdx.x;
  int b = blockIdx.x >> 5;
  int chunk = blockIdx.x & 31;
  int wid = t >> 6, lane = t & 63;
  for (int i = t; i < SS*DD; i += 256) qgl[i] = qg[(size_t)b*SS*DD + i];
  if (t < 8) { qcl[t] = qc[b*8+t]; rsl[t] = 0.f; }
  int si = t >> 5, ni = t & 31;
  float axa[8] = {0.f,0.f,0.f,0.f,0.f,0.f,0.f,0.f};
  for (int tile = 0; tile < 2; ++tile) {
    int n0 = (chunk*2 + tile) * 32;
    __syncthreads();
#pragma unroll
    for (int rr = 0; rr < 8; ++rr) {
      int r = wid*8 + rr;
      const float4* src = (const float4*)(inputs + ((size_t)b*NT + n0 + r)*DD);
      float4 x = src[lane];
      float sv = wredsum(x.x + x.y + x.z + x.w);
      float sq = wredsum(x.x*x.x + x.y*x.y + x.z*x.z + x.w*x.w);
      float mu = sv*(1.f/DD), var = sq*(1.f/DD)-mu*mu, rs = rsqrtf(var+F_LNEPS);
      float4 o;
      o.x=(x.x-mu)*rs; o.y=(x.y-mu)*rs; o.z=(x.z-mu)*rs; o.w=(x.w-mu)*rs;
      *(float4*)&xt[r*260 + lane*4] = o;
    }
    __syncthreads();
    float acc = 0.f;
    {
      const float4* xr = (const float4*)&xt[ni*260];
      const float4* qr = (const float4*)&qgl[si*DD];
#pragma unroll 8
      for (int j = 0; j < 64; ++j) {
        float4 a4 = xr[j]; float4 b4 = qr[j];
        acc += a4.x*b4.x + a4.y*b4.y + a4.z*b4.z + a4.w*b4.w;
      }
    }
    float dot = (acc + qcl[si]) * F_SCALE;
    dl[si*33+ni] = dot;
    __syncthreads();
    float m = dl[ni];
#pragma unroll
    for (int ss2 = 1; ss2 < 8; ++ss2) m = fmaxf(m, dl[ss2*33+ni]);
    float den = 0.f;
#pragma unroll
    for (int ss2 = 0; ss2 < 8; ++ss2) den += __expf(dl[ss2*33+ni] - m);
    float a = __expf(dot - m) / den + F_EPS;
    __syncthreads();
    dl[si*33+ni] = a;
    float rv = a;
#pragma unroll
    for (int mm = 16; mm > 0; mm >>= 1) rv += __shfl_xor(rv, mm, 64);
    if (ni == 0) rsl[si] += rv;
    if (write_attn) attn_out[(size_t)(b*8+si)*NT + n0 + ni] = a;
    __syncthreads();
#pragma unroll
    for (int n = 0; n < 32; ++n) {
      float x = xt[n*260 + t];
#pragma unroll
      for (int ss2 = 0; ss2 < 8; ++ss2) axa[ss2] += dl[ss2*33+n] * x;
    }
  }
#pragma unroll
  for (int ss2 = 0; ss2 < 8; ++ss2)
    atomicAdd(&axun[(size_t)(b*8+ss2)*DD + t], axa[ss2]);
  __syncthreads();
  if (t < 8) atomicAdd(&rsum[b*8+t], rsl[t]);
}

// ---------------- k_gru2: gh = Whh.slots+bhh ; gi = Wiv.xv+ci ; GRU -> smid ----------------
// 64 blocks (s,jc) x 512 threads: half 0 streams Whh, half 1 streams Wiv concurrently.
__global__ __launch_bounds__(512) void k_gru2(
    const float* __restrict__ slots, const float* __restrict__ axun,
    const float* __restrict__ rsum, const float* __restrict__ g_in,
    const float* __restrict__ Whh, const float* __restrict__ bhh,
    const float* __restrict__ Wiv, const float* __restrict__ ci,
    float* __restrict__ smid) {
  __shared__ __align__(16) float X2s[8*288];
  __shared__ __align__(16) float X2v[8*288];
  __shared__ float partA[32*8*9];
  __shared__ float partB[32*8*9];
  __shared__ float ghl[3*256];
  __shared__ float gil[3*256];
  int blk = blockIdx.x;
  int s = blk >> 3, jc = blk & 7, jb = jc*32;
  int t = threadIdx.x;
  int half = t >> 8, tid = t & 255;
  if (half == 0) {
    for (int i = tid; i < 2048; i += 256) {
      int b = i >> 8, d = i & 255;
      X2s[x2i(b,d)] = slots[(size_t)(b*8+s)*DD + d];
    }
  } else {
    for (int i = tid; i < 2048; i += 256) {
      int b = i >> 8, d = i & 255;
      X2v[x2i(b,d)] = axun[(size_t)(b*8+s)*DD + d] / rsum[b*8+s] * g_in[s*DD+d];
    }
  }
  // 3 gate tiles per half, lockstep (gemv32h does 2 block-wide syncs per call)
  for (int g = 0; g < 3; ++g) {
    const float* W = half ? (Wiv + ((size_t)s*768 + g*256 + jb)*DD)
                          : (Whh + ((size_t)s*768 + g*256 + jb)*DD);
    const float* X = half ? X2v : X2s;
    float* pt = half ? partB : partA;
    float* out = half ? gil : ghl;
    const float* bias = half ? ci : bhh;
    gemv32h(W, X, pt, tid, [&](int o,int b,float v){
      out[g*256 + o*8 + b] = v + bias[s*768 + g*256 + jb + o];
    });
  }
  __syncthreads();
  if (half == 0) {
    int o = tid >> 3, b = tid & 7;
    int d = jb + o;
    float hprev = X2s[x2i(b,d)];
    float r = sigm(gil[o*8+b] + ghl[o*8+b]);
    float z = sigm(gil[256 + o*8+b] + ghl[256 + o*8+b]);
    float nn2 = tanhfast(gil[512 + o*8+b] + r*ghl[512 + o*8+b]);
    smid[(size_t)(b*8+s)*DD + d] = (1.f - z)*nn2 + z*hprev;
  }
}

// ---------------- MLP layer 1 (round-3 verbatim) ----------------
__global__ __launch_bounds__(256) void k_mlp1(
    const float* __restrict__ smid, const float* __restrict__ g_pf,
    const float* __restrict__ b_pf, const float* __restrict__ W1,
    const float* __restrict__ b1, float* __restrict__ h1b) {
  __shared__ __align__(16) float X2[8*288];
  __shared__ float part[32*8*9];
  int blk = blockIdx.x;
  int s = blk >> 3, rc = blk & 7;
  int t = threadIdx.x;
  int wid = t >> 6, lane = t & 63;
#pragma unroll
  for (int half = 0; half < 2; ++half) {
    int bb2 = wid + half*4;
    const float4* src = (const float4*)(smid + (size_t)(bb2*8+s)*DD);
    float4 x = src[lane];
    float sv = wredsum(x.x+x.y+x.z+x.w);
    float sq = wredsum(x.x*x.x + x.y*x.y + x.z*x.z + x.w*x.w);
    float mu = sv*(1.f/DD), var = sq*(1.f/DD)-mu*mu, rs = rsqrtf(var+F_LNEPS);
    float4 g4 = ((const float4*)(g_pf + s*DD))[lane];
    float4 p4 = ((const float4*)(b_pf + s*DD))[lane];
    int base = bb2*288 + (lane>>3)*36 + (lane&7)*4;
    X2[base]   = (x.x-mu)*rs*g4.x + p4.x;
    X2[base+1] = (x.y-mu)*rs*g4.y + p4.y;
    X2[base+2] = (x.z-mu)*rs*g4.z + p4.z;
    X2[base+3] = (x.w-mu)*rs*g4.w + p4.w;
  }
  gemv32(W1 + ((size_t)s*HH + rc*32)*DD, X2, part, [&](int o,int bb2,float v){
    float rr = v + b1[s*HH + rc*32 + o];
    h1b[(size_t)(bb2*8+s)*HH + rc*32 + o] = fmaxf(rr, 0.f);
  });
}

// ---------------- MLP layer 2 + residual (round-3 verbatim) ----------------
__global__ __launch_bounds__(256) void k_mlp2(
    const float* __restrict__ h1b, const float* __restrict__ W2,
    const float* __restrict__ b2, const float* __restrict__ smid,
    float* __restrict__ slots, float* __restrict__ out_slots, int last) {
  __shared__ __align__(16) float X2[8*288];
  __shared__ float part[32*8*9];
  int blk = blockIdx.x;
  int s = blk >> 3, rc = blk & 7;
  int t = threadIdx.x;
  for (int i = t; i < 2048; i += 256) {
    int bb2 = i >> 8, dd = i & 255;
    X2[x2i(bb2,dd)] = h1b[(size_t)(bb2*8+s)*HH + dd];
  }
  gemv32(W2 + ((size_t)s*DD + rc*32)*HH, X2, part, [&](int o,int bb2,float v){
    int d = rc*32 + o;
    size_t idx = (size_t)(bb2*8+s)*DD + d;
    float rr = v + b2[s*DD + d] + smid[idx];
    slots[idx] = rr;
    if (last) out_slots[idx] = rr;
  });
}

extern "C" void kernel_launch(void* const* d_in, const int* in_sizes, int n_in,
                              void* d_out, int out_size, void* d_ws, size_t ws_size,
                              hipStream_t stream) {
  (void)in_sizes; (void)n_in; (void)out_size; (void)ws_size;
  const float* inputs = (const float*)d_in[0];
  const float* noise  = (const float*)d_in[1];
  const float* smu    = (const float*)d_in[2];
  const float* slsig  = (const float*)d_in[3];
  const float* g_in   = (const float*)d_in[4];
  const float* b_in   = (const float*)d_in[5];
  const float* g_ns   = (const float*)d_in[6];
  const float* b_ns   = (const float*)d_in[7];
  const float* g_pf   = (const float*)d_in[8];
  const float* b_pf   = (const float*)d_in[9];
  const float* Wq  = (const float*)d_in[10];
  const float* bq  = (const float*)d_in[11];
  const float* Wk  = (const float*)d_in[12];
  const float* bk  = (const float*)d_in[13];
  const float* Wv  = (const float*)d_in[14];
  const float* bv  = (const float*)d_in[15];
  const float* Wih = (const float*)d_in[16];
  const float* bih = (const float*)d_in[17];
  const float* Whh = (const float*)d_in[18];
  const float* bhh = (const float*)d_in[19];
  const float* W1  = (const float*)d_in[20];
  const float* b1  = (const float*)d_in[21];
  const float* W2  = (const float*)d_in[22];
  const float* b2  = (const float*)d_in[23];

  float* ws = (float*)d_ws;
  float* slots  = ws;                 ws += BB*SS*DD;        // 16384
  float* smid   = ws;                 ws += BB*SS*DD;        // 16384
  float* ck     = ws;                 ws += SS*DD;           // 2048
  float* cv     = ws;                 ws += SS*DD;           // 2048
  float* qg     = ws;                 ws += BB*SS*DD;        // 16384
  float* qc     = ws;                 ws += 64;
  float* rsum   = ws;                 ws += 64;
  float* axun   = ws;                 ws += BB*SS*DD;        // 16384
  float* h1b    = ws;                 ws += BB*SS*HH;        // 16384
  float* vq     = ws;                 ws += SS*DD;           // 2048
  float* qcon   = ws;                 ws += SS*DD;           // 2048
  float* c0     = ws;                 ws += 64;
  float* ci     = ws;                 ws += SS*768;          // 6144
  float* Pg     = ws;                 ws += (size_t)SS*DD*DD;   // 2 MB
  float* Wiv    = ws;                 ws += (size_t)SS*768*DD;  // 6 MB
  // total ~8.4 MB of f32 workspace

  float* out_slots = (float*)d_out;                          // f32 outputs
  float* out_attn  = out_slots + BB*SS*DD;

  k_init<<<dim3(96), dim3(256), 0, stream>>>(Wk, bk, Wv, bv, b_in, smu, slsig, noise,
                                             ck, cv, slots);
  k_init2<<<dim3(528), dim3(256), 0, stream>>>(Wq, Wk, bq, ck, g_in, Pg, vq, qcon, c0);
  k_init2b<<<dim3(1728), dim3(256), 0, stream>>>(Wih, Wv, cv, bih, Wiv, ci);
  k_q2<<<dim3(64), dim3(256), 0, stream>>>(slots, g_ns, b_ns, Pg, qcon, vq, c0,
                                           qg, qc, axun, rsum);
  for (int it = 0; it < 3; ++it) {
    int last = (it == 2) ? 1 : 0;
    k_dots<<<dim3(256), dim3(256), 0, stream>>>(inputs, qg, qc, axun, rsum,
                                                out_attn, last);
    k_gru2<<<dim3(64), dim3(512), 0, stream>>>(slots, axun, rsum, g_in,
                                               Whh, bhh, Wiv, ci, smid);
    k_mlp1<<<dim3(64), dim3(256), 0, stream>>>(smid, g_pf, b_pf, W1, b1, h1b);
    k_mlp2<<<dim3(64), dim3(256), 0, stream>>>(h1b, W2, b2, smid, slots,
                                               out_slots, last);
    if (!last)
      k_q2<<<dim3(64), dim3(256), 0, stream>>>(slots, g_ns, b_ns, Pg, qcon, vq, c0,
                                               qg, qc, axun, rsum);
  }
}

// Round 11
// 181.954 us; speedup vs baseline: 2.1135x; 1.1853x over previous
//
#include <hip/hip_runtime.h>

// Slot Attention fwd, B=8 N=2048 D=256 S=8 H=256 ITERS=3.  All f32.
// Multi-kernel (17 launches):
//   Pg[s]  = diag(g_in[s]) * Wk[s]^T Wq[s]         (setup, reg-blocked GEMM)
//   Wiv[s] = Wih[s] @ Wv[s],  ci[s] = Wih.cv + bih (setup; upd never exists)
//   qg[b,s] = Pg[s]*sn + qcon[s],  qc = sn.vq[s] + c0[s]
//   dots[b,s,n] = SCALE*( xn[b,n,:].qg[b,s,:] + qc )
//   gi = Wiv.xv + ci,  gh = Whh.slots + bhh,  xv = ax*g_in/rsum
// xn = LN(inputs) recomputed on the fly in k_dots (never stored).

#define BB 8
#define NT 2048
#define DD 256
#define SS 8
#define HH 256

static constexpr float F_EPS   = 1e-8f;
static constexpr float F_LNEPS = 1e-5f;
static constexpr float F_SCALE = 0.0625f;   // 256^-0.5

__device__ __forceinline__ float wredsum(float v) {
#pragma unroll
  for (int m = 32; m > 0; m >>= 1) v += __shfl_xor(v, m, 64);
  return v;
}
__device__ __forceinline__ float sigm(float x) { return 1.f / (1.f + __expf(-x)); }
__device__ __forceinline__ float tanhfast(float x) {
  float ax = fabsf(x);
  float e = __expf(2.f * ax);
  float t2 = 1.f - 2.f / (e + 1.f);
  return x < 0.f ? -t2 : t2;
}
// X2 LDS layout: (b,d) -> b*288 + (d>>5)*36 + (d&31)   (bank-conflict-free)
__device__ __forceinline__ int x2i(int bb, int dd) { return bb*288 + (dd>>5)*36 + (dd&31); }
__device__ __forceinline__ int xpi(int d) { return (d>>5)*36 + (d&31); }

// ---- b-batched 32-row GEMV: 256 thr; emit(o,b,v) on all threads ----
template <typename F>
__device__ __forceinline__ void gemv32(const float* __restrict__ Wrow0,
                                       const float* __restrict__ X2,
                                       float* __restrict__ part, F emit) {
  int t = threadIdx.x;
  int ol = t >> 3, dg = t & 7;
  const float4* wr = (const float4*)(Wrow0 + (size_t)ol*256 + (size_t)dg*32);
  __syncthreads();                 // X2 staged / part free
  float acc[8] = {0.f,0.f,0.f,0.f,0.f,0.f,0.f,0.f};
#pragma unroll
  for (int j = 0; j < 8; ++j) {
    float4 w4 = wr[j];
    int xo = dg*36 + 4*j;
#pragma unroll
    for (int bbi = 0; bbi < 8; ++bbi) {
      float4 x4 = *(const float4*)&X2[bbi*288 + xo];
      acc[bbi] = fmaf(w4.x,x4.x, fmaf(w4.y,x4.y, fmaf(w4.z,x4.z, fmaf(w4.w,x4.w, acc[bbi]))));
    }
  }
#pragma unroll
  for (int bbi = 0; bbi < 8; ++bbi) part[(ol*8+bbi)*9 + dg] = acc[bbi];
  __syncthreads();
  int o = t >> 3, bbo = t & 7;
  const float* pp = &part[(o*8+bbo)*9];
  float v = ((pp[0]+pp[1])+(pp[2]+pp[3]))+((pp[4]+pp[5])+(pp[6]+pp[7]));
  emit(o, bbo, v);
}

// same core, tid-parametrized (512-thread kernels run two halves in lockstep)
template <typename F>
__device__ __forceinline__ void gemv32h(const float* __restrict__ Wrow0,
                                        const float* __restrict__ X2,
                                        float* __restrict__ part, int tid, F emit) {
  int ol = tid >> 3, dg = tid & 7;
  const float4* wr = (const float4*)(Wrow0 + (size_t)ol*256 + (size_t)dg*32);
  __syncthreads();
  float acc[8] = {0.f,0.f,0.f,0.f,0.f,0.f,0.f,0.f};
#pragma unroll
  for (int j = 0; j < 8; ++j) {
    float4 w4 = wr[j];
    int xo = dg*36 + 4*j;
#pragma unroll
    for (int bbi = 0; bbi < 8; ++bbi) {
      float4 x4 = *(const float4*)&X2[bbi*288 + xo];
      acc[bbi] = fmaf(w4.x,x4.x, fmaf(w4.y,x4.y, fmaf(w4.z,x4.z, fmaf(w4.w,x4.w, acc[bbi]))));
    }
  }
#pragma unroll
  for (int bbi = 0; bbi < 8; ++bbi) part[(ol*8+bbi)*9 + dg] = acc[bbi];
  __syncthreads();
  int o = tid >> 3, bbo = tid & 7;
  const float* pp = &part[(o*8+bbo)*9];
  float v = ((pp[0]+pp[1])+(pp[2]+pp[3]))+((pp[4]+pp[5])+(pp[6]+pp[7]));
  emit(o, bbo, v);
}

// ---- sync-free single-vector GEMV tile (32 rows x 8 dg) ----
template <typename F>
__device__ __forceinline__ void gemv_tile(const float* __restrict__ Wrow0,
                                          const float* __restrict__ xp, F emit) {
  int t = threadIdx.x;
  int ol = t >> 3, dg = t & 7;
  const float4* wr = (const float4*)(Wrow0 + (size_t)ol*256 + dg*32);
  float acc = 0.f;
#pragma unroll
  for (int j = 0; j < 8; ++j) {
    float4 w4 = wr[j];
    float4 x4 = *(const float4*)&xp[dg*36 + 4*j];
    acc = fmaf(w4.x,x4.x, fmaf(w4.y,x4.y, fmaf(w4.z,x4.z, fmaf(w4.w,x4.w, acc))));
  }
  acc += __shfl_xor(acc, 1, 64);
  acc += __shfl_xor(acc, 2, 64);
  acc += __shfl_xor(acc, 4, 64);
  if ((t & 7) == 0) emit(ol, acc);
}

// ---------------- setup1: Pg & Wiv (reg-blocked 64x64 GEMM), slots, ck/cv ----------------
__global__ __launch_bounds__(256) void k_setup1(
    const float* __restrict__ Wq, const float* __restrict__ Wk,
    const float* __restrict__ Wv, const float* __restrict__ Wih,
    const float* __restrict__ bk, const float* __restrict__ bv,
    const float* __restrict__ b_in, const float* __restrict__ smu,
    const float* __restrict__ slsig, const float* __restrict__ noise,
    const float* __restrict__ g_in,
    float* __restrict__ Pg, float* __restrict__ Wiv,
    float* __restrict__ ck, float* __restrict__ cv,
    float* __restrict__ slots) {
  int blk = blockIdx.x;
  int t = threadIdx.x;
  if (blk < 512) {
    // GEMM tiles: blk<128 -> Pg (8s x 4x4 tiles); else Wiv (8s x 12x4 tiles)
    __shared__ __align__(16) float As[32*68];
    __shared__ __align__(16) float Bs[32*68];
    bool isPg = blk < 128;
    int s, d0, e0;
    if (isPg) { s = blk >> 4; int tl2 = blk & 15; d0 = (tl2>>2)*64; e0 = (tl2&3)*64; }
    else { int b2 = blk-128; s = b2/48; int rem = b2%48; d0 = (rem>>2)*64; e0 = (rem&3)*64; }
    int ty = t >> 4, tx = t & 15;
    float acc[4][4] = {{0.f,0.f,0.f,0.f},{0.f,0.f,0.f,0.f},{0.f,0.f,0.f,0.f},{0.f,0.f,0.f,0.f}};
    const float* Abase = isPg ? (Wk + (size_t)s*DD*DD) : (Wih + (size_t)s*768*DD);
    const float* Bbase = isPg ? (Wq + (size_t)s*DD*DD) : (Wv + (size_t)s*DD*DD);
    for (int o0 = 0; o0 < DD; o0 += 32) {
      __syncthreads();
      if (isPg) {
        // As[o][d] = Wk[o0+o][d0+d] (direct, coalesced float4)
        for (int l = t; l < 512; l += 256) {
          int o = l >> 4, dq = l & 15;
          *(float4*)&As[o*68 + dq*4] = *(const float4*)&Abase[(size_t)(o0+o)*DD + d0 + dq*4];
        }
      } else {
        // As[o][r] = Wih[d0+r][o0+o] (transpose on store)
        for (int l = t; l < 512; l += 256) {
          int r = l >> 3, oq = l & 7;
          float4 v = *(const float4*)&Abase[(size_t)(d0+r)*DD + o0 + oq*4];
          As[(oq*4+0)*68 + r] = v.x;
          As[(oq*4+1)*68 + r] = v.y;
          As[(oq*4+2)*68 + r] = v.z;
          As[(oq*4+3)*68 + r] = v.w;
        }
      }
      for (int l = t; l < 512; l += 256) {
        int o = l >> 4, eq = l & 15;
        *(float4*)&Bs[o*68 + eq*4] = *(const float4*)&Bbase[(size_t)(o0+o)*DD + e0 + eq*4];
      }
      __syncthreads();
#pragma unroll 8
      for (int o = 0; o < 32; ++o) {
        float4 a4 = *(const float4*)&As[o*68 + ty*4];
        float4 b4 = *(const float4*)&Bs[o*68 + tx*4];
        float av[4] = {a4.x,a4.y,a4.z,a4.w};
        float bw[4] = {b4.x,b4.y,b4.z,b4.w};
#pragma unroll
        for (int i = 0; i < 4; ++i)
#pragma unroll
          for (int j = 0; j < 4; ++j)
            acc[i][j] = fmaf(av[i], bw[j], acc[i][j]);
      }
    }
    if (isPg) {
#pragma unroll
      for (int i = 0; i < 4; ++i) {
        int d = d0 + ty*4 + i;
        float g = g_in[s*DD + d];
        float4 o4 = {g*acc[i][0], g*acc[i][1], g*acc[i][2], g*acc[i][3]};
        *(float4*)&Pg[((size_t)s*DD + d)*DD + e0 + tx*4] = o4;
      }
    } else {
#pragma unroll
      for (int i = 0; i < 4; ++i) {
        int r = d0 + ty*4 + i;
        float4 o4 = {acc[i][0], acc[i][1], acc[i][2], acc[i][3]};
        *(float4*)&Wiv[((size_t)s*768 + r)*DD + e0 + tx*4] = o4;
      }
    }
  } else if (blk < 576) {
    int idx = (blk-512)*256 + t;       // < B*S*D
    int sd = idx & 2047;
    slots[idx] = smu[sd] + __expf(slsig[sd]) * noise[idx];
  } else {
    // ck/cv: 32 blocks
    int bb = blk - 576;
    int s = bb >> 2, oq = bb & 3;
    int wid = t >> 6, lane = t & 63;
    float4 bi = ((const float4*)(b_in + s*DD))[lane];
    for (int r = 0; r < 16; ++r) {
      int o = oq*64 + wid*16 + r;
      float4 wk4 = ((const float4*)(Wk + ((size_t)s*DD + o)*DD))[lane];
      float4 wv4 = ((const float4*)(Wv + ((size_t)s*DD + o)*DD))[lane];
      float pk = wredsum(bi.x*wk4.x + bi.y*wk4.y + bi.z*wk4.z + bi.w*wk4.w);
      float pv = wredsum(bi.x*wv4.x + bi.y*wv4.y + bi.z*wv4.z + bi.w*wv4.w);
      if (lane == 0) {
        ck[s*DD+o] = pk + bk[s*DD+o];
        cv[s*DD+o] = pv + bv[s*DD+o];
      }
    }
  }
}

// ---------------- setup2: vq/qcon/c0 (need ck) ; ci = Wih.cv + bih (needs cv) ----------------
__global__ __launch_bounds__(256) void k_setup2(
    const float* __restrict__ Wq, const float* __restrict__ Wk,
    const float* __restrict__ Wih, const float* __restrict__ bq,
    const float* __restrict__ bih, const float* __restrict__ ck,
    const float* __restrict__ cv, const float* __restrict__ g_in,
    float* __restrict__ vq, float* __restrict__ qcon,
    float* __restrict__ c0, float* __restrict__ ci) {
  __shared__ __align__(16) float sm[8*264];
  int blk = blockIdx.x;
  int t = threadIdx.x;
  if (blk < 16) {
    float* cvec  = sm;            // reuse head as cvec (256) — part2 uses full sm after sync
    __shared__ float part2[8*264];
    int s = blk >> 1, which = blk & 1;
    const float* W = which ? Wk : Wq;
    const float* vec = which ? bq : ck;
    cvec[t] = vec[s*DD + t];
    __syncthreads();
    int og = t >> 5, eg = t & 31;
    float acc[8] = {0.f,0.f,0.f,0.f,0.f,0.f,0.f,0.f};
    for (int oi = 0; oi < 32; ++oi) {
      int o = og*32 + oi;
      float cw = cvec[o];
      const float4* wrow = (const float4*)(W + ((size_t)s*DD + o)*DD + eg*8);
      float4 w0 = wrow[0], w1 = wrow[1];
      acc[0] += w0.x*cw; acc[1] += w0.y*cw; acc[2] += w0.z*cw; acc[3] += w0.w*cw;
      acc[4] += w1.x*cw; acc[5] += w1.y*cw; acc[6] += w1.z*cw; acc[7] += w1.w*cw;
    }
#pragma unroll
    for (int j = 0; j < 8; ++j) part2[og*264 + eg*8 + j] = acc[j];
    __syncthreads();
    float v = 0.f;
#pragma unroll
    for (int og2 = 0; og2 < 8; ++og2) v += part2[og2*264 + t];
    if (which) qcon[s*DD + t] = v * g_in[s*DD + t];
    else       vq[s*DD + t]   = v;
    if (which == 0 && t < 64) {
      float4 b4 = ((const float4*)(bq + s*DD))[t];
      float4 c4 = ((const float4*)(ck + s*DD))[t];
      float vv = wredsum(b4.x*c4.x + b4.y*c4.y + b4.z*c4.z + b4.w*c4.w);
      if (t == 0) c0[s] = vv;
    }
  } else {
    // ci: 192 blocks = 8 slots x 24 row-tiles
    float* xp = sm;               // 288 used
    int idx = blk - 16;
    int s = idx / 24, jt = idx % 24;
    xp[xpi(t)] = cv[s*DD + t];
    __syncthreads();
    gemv_tile(Wih + ((size_t)s*768 + jt*32)*DD, xp, [&](int o, float v){
      ci[s*768 + jt*32 + o] = v + bih[s*768 + jt*32 + o];
    });
  }
}

// ---------------- per-iter q-chain: sn, qg, qc; zero ax/rs ----------------
__global__ __launch_bounds__(256) void k_q2(
    const float* __restrict__ slots, const float* __restrict__ g_ns,
    const float* __restrict__ b_ns, const float* __restrict__ Pg,
    const float* __restrict__ qcon, const float* __restrict__ vq,
    const float* __restrict__ c0,
    float* __restrict__ qg, float* __restrict__ qc,
    float* __restrict__ axun, float* __restrict__ rsum) {
  __shared__ __align__(16) float X2[8*288];
  __shared__ float part[32*8*9];
  int blk = blockIdx.x;
  int s = blk >> 3, rc = blk & 7;
  int t = threadIdx.x;
  int wid = t >> 6, lane = t & 63;
  float4 g4 = ((const float4*)(g_ns + s*DD))[lane];
  float4 p4 = ((const float4*)(b_ns + s*DD))[lane];
#pragma unroll
  for (int half = 0; half < 2; ++half) {
    int bb2 = wid + half*4;
    const float4* src = (const float4*)(slots + (size_t)(bb2*8+s)*DD);
    float4 x = src[lane];
    float sv = wredsum(x.x+x.y+x.z+x.w);
    float sq = wredsum(x.x*x.x + x.y*x.y + x.z*x.z + x.w*x.w);
    float mu = sv*(1.f/DD), var = sq*(1.f/DD)-mu*mu, rs = rsqrtf(var+F_LNEPS);
    int base = bb2*288 + (lane>>3)*36 + (lane&7)*4;
    X2[base]   = (x.x-mu)*rs*g4.x + p4.x;
    X2[base+1] = (x.y-mu)*rs*g4.y + p4.y;
    X2[base+2] = (x.z-mu)*rs*g4.z + p4.z;
    X2[base+3] = (x.w-mu)*rs*g4.w + p4.w;
  }
  if (rc == 0) {
    for (int i = t; i < 2048; i += 256) {
      int bb2 = i >> 8, dd = i & 255;
      axun[(size_t)(bb2*8+s)*DD + dd] = 0.f;     // zero accumulators for k_dots
    }
    if (t < 8) rsum[t*8+s] = 0.f;
  }
  __syncthreads();
  if (rc == 0) {           // qc for all 8 b's of this slot
    int b = t >> 5, l32 = t & 31;
    float v = 0.f;
#pragma unroll
    for (int j = 0; j < 8; ++j)
      v += X2[b*288 + j*36 + l32] * vq[s*DD + j*32 + l32];
#pragma unroll
    for (int m = 16; m > 0; m >>= 1) v += __shfl_xor(v, m, 64);
    if (l32 == 0) qc[b*8+s] = v + c0[s];
  }
  gemv32(Pg + ((size_t)s*DD + rc*32)*DD, X2, part, [&](int o,int bb2,float v){
    qg[(size_t)(bb2*8+s)*DD + rc*32 + o] = v + qcon[s*DD + rc*32 + o];
  });
}

// ---------------- heavy: LN(inputs)+dots+softmax+ax atomics ----------------
__global__ __launch_bounds__(256) void k_dots(
    const float* __restrict__ inputs, const float* __restrict__ qg,
    const float* __restrict__ qc, float* __restrict__ axun,
    float* __restrict__ rsum, float* __restrict__ attn_out, int write_attn) {
  __shared__ __align__(16) float qgl[SS*DD];   // 8 KB
  __shared__ __align__(16) float xt[32*260];   // 33.3 KB
  __shared__ float dl[8*33];
  __shared__ float qcl[8];
  __shared__ float rsl[8];
  int t = threadIdx.x;
  int b = blockIdx.x >> 5;
  int chunk = blockIdx.x & 31;
  int wid = t >> 6, lane = t & 63;
  for (int i = t; i < SS*DD; i += 256) qgl[i] = qg[(size_t)b*SS*DD + i];
  if (t < 8) { qcl[t] = qc[b*8+t]; rsl[t] = 0.f; }
  int si = t >> 5, ni = t & 31;
  float axa[8] = {0.f,0.f,0.f,0.f,0.f,0.f,0.f,0.f};
  for (int tile = 0; tile < 2; ++tile) {
    int n0 = (chunk*2 + tile) * 32;
    __syncthreads();
#pragma unroll
    for (int rr = 0; rr < 8; ++rr) {
      int r = wid*8 + rr;
      const float4* src = (const float4*)(inputs + ((size_t)b*NT + n0 + r)*DD);
      float4 x = src[lane];
      float sv = wredsum(x.x + x.y + x.z + x.w);
      float sq = wredsum(x.x*x.x + x.y*x.y + x.z*x.z + x.w*x.w);
      float mu = sv*(1.f/DD), var = sq*(1.f/DD)-mu*mu, rs = rsqrtf(var+F_LNEPS);
      float4 o;
      o.x=(x.x-mu)*rs; o.y=(x.y-mu)*rs; o.z=(x.z-mu)*rs; o.w=(x.w-mu)*rs;
      *(float4*)&xt[r*260 + lane*4] = o;
    }
    __syncthreads();
    float acc = 0.f;
    {
      const float4* xr = (const float4*)&xt[ni*260];
      const float4* qr = (const float4*)&qgl[si*DD];
#pragma unroll 8
      for (int j = 0; j < 64; ++j) {
        float4 a4 = xr[j]; float4 b4 = qr[j];
        acc += a4.x*b4.x + a4.y*b4.y + a4.z*b4.z + a4.w*b4.w;
      }
    }
    float dot = (acc + qcl[si]) * F_SCALE;
    dl[si*33+ni] = dot;
    __syncthreads();
    float m = dl[ni];
#pragma unroll
    for (int ss2 = 1; ss2 < 8; ++ss2) m = fmaxf(m, dl[ss2*33+ni]);
    float den = 0.f;
#pragma unroll
    for (int ss2 = 0; ss2 < 8; ++ss2) den += __expf(dl[ss2*33+ni] - m);
    float a = __expf(dot - m) / den + F_EPS;
    __syncthreads();
    dl[si*33+ni] = a;
    float rv = a;
#pragma unroll
    for (int mm = 16; mm > 0; mm >>= 1) rv += __shfl_xor(rv, mm, 64);
    if (ni == 0) rsl[si] += rv;
    if (write_attn) attn_out[(size_t)(b*8+si)*NT + n0 + ni] = a;
    __syncthreads();
#pragma unroll
    for (int n = 0; n < 32; ++n) {
      float x = xt[n*260 + t];
#pragma unroll
      for (int ss2 = 0; ss2 < 8; ++ss2) axa[ss2] += dl[ss2*33+n] * x;
    }
  }
#pragma unroll
  for (int ss2 = 0; ss2 < 8; ++ss2)
    atomicAdd(&axun[(size_t)(b*8+ss2)*DD + t], axa[ss2]);
  __syncthreads();
  if (t < 8) atomicAdd(&rsum[b*8+t], rsl[t]);
}

// ---------------- k_gru2: gh = Whh.slots+bhh ; gi = Wiv.xv+ci ; GRU -> smid ----------------
__global__ __launch_bounds__(512) void k_gru2(
    const float* __restrict__ slots, const float* __restrict__ axun,
    const float* __restrict__ rsum, const float* __restrict__ g_in,
    const float* __restrict__ Whh, const float* __restrict__ bhh,
    const float* __restrict__ Wiv, const float* __restrict__ ci,
    float* __restrict__ smid) {
  __shared__ __align__(16) float X2s[8*288];
  __shared__ __align__(16) float X2v[8*288];
  __shared__ float partA[32*8*9];
  __shared__ float partB[32*8*9];
  __shared__ float ghl[3*256];
  __shared__ float gil[3*256];
  int blk = blockIdx.x;
  int s = blk >> 3, jc = blk & 7, jb = jc*32;
  int t = threadIdx.x;
  int half = t >> 8, tid = t & 255;
  if (half == 0) {
    for (int i = tid; i < 2048; i += 256) {
      int b = i >> 8, d = i & 255;
      X2s[x2i(b,d)] = slots[(size_t)(b*8+s)*DD + d];
    }
  } else {
    for (int i = tid; i < 2048; i += 256) {
      int b = i >> 8, d = i & 255;
      X2v[x2i(b,d)] = axun[(size_t)(b*8+s)*DD + d] / rsum[b*8+s] * g_in[s*DD+d];
    }
  }
  for (int g = 0; g < 3; ++g) {
    const float* W = half ? (Wiv + ((size_t)s*768 + g*256 + jb)*DD)
                          : (Whh + ((size_t)s*768 + g*256 + jb)*DD);
    const float* X = half ? X2v : X2s;
    float* pt = half ? partB : partA;
    float* out = half ? gil : ghl;
    const float* bias = half ? ci : bhh;
    gemv32h(W, X, pt, tid, [&](int o,int b,float v){
      out[g*256 + o*8 + b] = v + bias[s*768 + g*256 + jb + o];
    });
  }
  __syncthreads();
  if (half == 0) {
    int o = tid >> 3, b = tid & 7;
    int d = jb + o;
    float hprev = X2s[x2i(b,d)];
    float r = sigm(gil[o*8+b] + ghl[o*8+b]);
    float z = sigm(gil[256 + o*8+b] + ghl[256 + o*8+b]);
    float nn2 = tanhfast(gil[512 + o*8+b] + r*ghl[512 + o*8+b]);
    smid[(size_t)(b*8+s)*DD + d] = (1.f - z)*nn2 + z*hprev;
  }
}

// ---------------- MLP layer 1 ----------------
__global__ __launch_bounds__(256) void k_mlp1(
    const float* __restrict__ smid, const float* __restrict__ g_pf,
    const float* __restrict__ b_pf, const float* __restrict__ W1,
    const float* __restrict__ b1, float* __restrict__ h1b) {
  __shared__ __align__(16) float X2[8*288];
  __shared__ float part[32*8*9];
  int blk = blockIdx.x;
  int s = blk >> 3, rc = blk & 7;
  int t = threadIdx.x;
  int wid = t >> 6, lane = t & 63;
#pragma unroll
  for (int half = 0; half < 2; ++half) {
    int bb2 = wid + half*4;
    const float4* src = (const float4*)(smid + (size_t)(bb2*8+s)*DD);
    float4 x = src[lane];
    float sv = wredsum(x.x+x.y+x.z+x.w);
    float sq = wredsum(x.x*x.x + x.y*x.y + x.z*x.z + x.w*x.w);
    float mu = sv*(1.f/DD), var = sq*(1.f/DD)-mu*mu, rs = rsqrtf(var+F_LNEPS);
    float4 g4 = ((const float4*)(g_pf + s*DD))[lane];
    float4 p4 = ((const float4*)(b_pf + s*DD))[lane];
    int base = bb2*288 + (lane>>3)*36 + (lane&7)*4;
    X2[base]   = (x.x-mu)*rs*g4.x + p4.x;
    X2[base+1] = (x.y-mu)*rs*g4.y + p4.y;
    X2[base+2] = (x.z-mu)*rs*g4.z + p4.z;
    X2[base+3] = (x.w-mu)*rs*g4.w + p4.w;
  }
  gemv32(W1 + ((size_t)s*HH + rc*32)*DD, X2, part, [&](int o,int bb2,float v){
    float rr = v + b1[s*HH + rc*32 + o];
    h1b[(size_t)(bb2*8+s)*HH + rc*32 + o] = fmaxf(rr, 0.f);
  });
}

// ---------------- MLP layer 2 + residual ----------------
__global__ __launch_bounds__(256) void k_mlp2(
    const float* __restrict__ h1b, const float* __restrict__ W2,
    const float* __restrict__ b2, const float* __restrict__ smid,
    float* __restrict__ slots, float* __restrict__ out_slots, int last) {
  __shared__ __align__(16) float X2[8*288];
  __shared__ float part[32*8*9];
  int blk = blockIdx.x;
  int s = blk >> 3, rc = blk & 7;
  int t = threadIdx.x;
  for (int i = t; i < 2048; i += 256) {
    int bb2 = i >> 8, dd = i & 255;
    X2[x2i(bb2,dd)] = h1b[(size_t)(bb2*8+s)*HH + dd];
  }
  gemv32(W2 + ((size_t)s*DD + rc*32)*HH, X2, part, [&](int o,int bb2,float v){
    int d = rc*32 + o;
    size_t idx = (size_t)(bb2*8+s)*DD + d;
    float rr = v + b2[s*DD + d] + smid[idx];
    slots[idx] = rr;
    if (last) out_slots[idx] = rr;
  });
}

extern "C" void kernel_launch(void* const* d_in, const int* in_sizes, int n_in,
                              void* d_out, int out_size, void* d_ws, size_t ws_size,
                              hipStream_t stream) {
  (void)in_sizes; (void)n_in; (void)out_size; (void)ws_size;
  const float* inputs = (const float*)d_in[0];
  const float* noise  = (const float*)d_in[1];
  const float* smu    = (const float*)d_in[2];
  const float* slsig  = (const float*)d_in[3];
  const float* g_in   = (const float*)d_in[4];
  const float* b_in   = (const float*)d_in[5];
  const float* g_ns   = (const float*)d_in[6];
  const float* b_ns   = (const float*)d_in[7];
  const float* g_pf   = (const float*)d_in[8];
  const float* b_pf   = (const float*)d_in[9];
  const float* Wq  = (const float*)d_in[10];
  const float* bq  = (const float*)d_in[11];
  const float* Wk  = (const float*)d_in[12];
  const float* bk  = (const float*)d_in[13];
  const float* Wv  = (const float*)d_in[14];
  const float* bv  = (const float*)d_in[15];
  const float* Wih = (const float*)d_in[16];
  const float* bih = (const float*)d_in[17];
  const float* Whh = (const float*)d_in[18];
  const float* bhh = (const float*)d_in[19];
  const float* W1  = (const float*)d_in[20];
  const float* b1  = (const float*)d_in[21];
  const float* W2  = (const float*)d_in[22];
  const float* b2  = (const float*)d_in[23];

  float* ws = (float*)d_ws;
  float* slots  = ws;                 ws += BB*SS*DD;        // 16384
  float* smid   = ws;                 ws += BB*SS*DD;        // 16384
  float* ck     = ws;                 ws += SS*DD;           // 2048
  float* cv     = ws;                 ws += SS*DD;           // 2048
  float* qg     = ws;                 ws += BB*SS*DD;        // 16384
  float* qc     = ws;                 ws += 64;
  float* rsum   = ws;                 ws += 64;
  float* axun   = ws;                 ws += BB*SS*DD;        // 16384
  float* h1b    = ws;                 ws += BB*SS*HH;        // 16384
  float* vq     = ws;                 ws += SS*DD;           // 2048
  float* qcon   = ws;                 ws += SS*DD;           // 2048
  float* c0     = ws;                 ws += 64;
  float* ci     = ws;                 ws += SS*768;          // 6144
  float* Pg     = ws;                 ws += (size_t)SS*DD*DD;   // 2 MB
  float* Wiv    = ws;                 ws += (size_t)SS*768*DD;  // 6 MB
  // total ~8.4 MB of f32 workspace

  float* out_slots = (float*)d_out;                          // f32 outputs
  float* out_attn  = out_slots + BB*SS*DD;

  k_setup1<<<dim3(608), dim3(256), 0, stream>>>(Wq, Wk, Wv, Wih, bk, bv, b_in,
                                                smu, slsig, noise, g_in,
                                                Pg, Wiv, ck, cv, slots);
  k_setup2<<<dim3(208), dim3(256), 0, stream>>>(Wq, Wk, Wih, bq, bih, ck, cv, g_in,
                                                vq, qcon, c0, ci);
  k_q2<<<dim3(64), dim3(256), 0, stream>>>(slots, g_ns, b_ns, Pg, qcon, vq, c0,
                                           qg, qc, axun, rsum);
  for (int it = 0; it < 3; ++it) {
    int last = (it == 2) ? 1 : 0;
    k_dots<<<dim3(256), dim3(256), 0, stream>>>(inputs, qg, qc, axun, rsum,
                                                out_attn, last);
    k_gru2<<<dim3(64), dim3(512), 0, stream>>>(slots, axun, rsum, g_in,
                                               Whh, bhh, Wiv, ci, smid);
    k_mlp1<<<dim3(64), dim3(256), 0, stream>>>(smid, g_pf, b_pf, W1, b1, h1b);
    k_mlp2<<<dim3(64), dim3(256), 0, stream>>>(h1b, W2, b2, smid, slots,
                                               out_slots, last);
    if (!last)
      k_q2<<<dim3(64), dim3(256), 0, stream>>>(slots, g_ns, b_ns, Pg, qcon, vq, c0,
                                               qg, qc, axun, rsum);
  }
}